// Round 13
// baseline (201.316 us; speedup 1.0000x reference)
//
#include <hip/hip_runtime.h>
#include <math.h>

typedef __attribute__((ext_vector_type(8))) short bf16x8;
typedef __attribute__((ext_vector_type(4))) float f32x4;
typedef __attribute__((ext_vector_type(8))) unsigned short ushort8;

#define N_IMT  (8*136*136*16)     // imTp: [b][136r][136c][16ch] bf16 (hi or lo)
#define N_PT   (8*66*66*64)       // poolTp: [b][66][66][64] bf16
#define N_X2   (8*128*64*64)
#define N_PARTIAL (8*32*8*128)
#define N_WB1  (25*4*64*8)
#define N_WB2  (18*8*64*8)

__device__ inline unsigned short f2bf(float f) {
    unsigned u = __float_as_uint(f);
    u += 0x7FFF + ((u >> 16) & 1);          // RNE
    return (unsigned short)(u >> 16);
}
__device__ inline float bf2f(unsigned short h) {
    return __uint_as_float(((unsigned)h) << 16);
}

// ---- k_zero: zero imTp_hi/lo + poolTp_hi/lo (borders + pad channels) ----
__global__ void k_zero(unsigned* __restrict__ p, int n) {
    int stride = gridDim.x * 256;
    for (int i = blockIdx.x * 256 + threadIdx.x; i < n; i += stride) p[i] = 0u;
}

// ---- k_prep: transpose/split images -> imTp; pack weights -> per-frag slabs ----
__global__ void k_prep(const float* __restrict__ images,
                       const float* __restrict__ w1, const float* __restrict__ w2,
                       unsigned short* __restrict__ imTh, unsigned short* __restrict__ imTl,
                       unsigned short* __restrict__ wB1h, unsigned short* __restrict__ wB1l,
                       unsigned short* __restrict__ wB2h, unsigned short* __restrict__ wB2l)
{
    const int bid = blockIdx.x, tid = threadIdx.x;
    if (bid < 512) {
        int t = bid * 256 + tid;              // (b,y,x) over 8*128*128
        int b = t >> 14, rem = t & 16383;
        int y = rem >> 7, x = rem & 127;
        ushort8 h0, h1, l0, l1;
        #pragma unroll
        for (int j = 0; j < 8; ++j) {
            float v = images[((b * 12 + j) << 14) + (y << 7) + x];
            unsigned short h = f2bf(v);
            h0[j] = h; l0[j] = f2bf(v - bf2f(h));
        }
        #pragma unroll
        for (int j = 0; j < 4; ++j) {
            float v = images[((b * 12 + 8 + j) << 14) + (y << 7) + x];
            unsigned short h = f2bf(v);
            h1[j] = h; l1[j] = f2bf(v - bf2f(h));
        }
        #pragma unroll
        for (int j = 4; j < 8; ++j) { h1[j] = 0; l1[j] = 0; }
        int base = ((b * 136 + y + 3) * 136 + x + 3) * 16;
        *(ushort8*)(imTh + base) = h0;  *(ushort8*)(imTh + base + 8) = h1;
        *(ushort8*)(imTl + base) = l0;  *(ushort8*)(imTl + base + 8) = l1;
    } else if (bid < 537) {
        // wB1[s][n][lane][8]: oc=n*16+(l&15); g=l>>4; tap=2s+(g>>1); ic=(g&1)*8+j
        int s = bid - 512;
        int n = tid >> 6, l = tid & 63;
        int oc = n * 16 + (l & 15), g = l >> 4;
        int tap = 2 * s + (g >> 1);
        ushort8 hi, lo;
        #pragma unroll
        for (int j = 0; j < 8; ++j) {
            int ic = (g & 1) * 8 + j;
            float v = (tap < 49 && ic < 12) ? w1[oc * 588 + ic * 49 + tap] : 0.0f;
            unsigned short h = f2bf(v);
            hi[j] = h; lo[j] = f2bf(v - bf2f(h));
        }
        int idx = ((s * 4 + n) * 64 + l) * 8;
        *(ushort8*)(wB1h + idx) = hi;  *(ushort8*)(wB1l + idx) = lo;
    } else {
        // wB2[s][n][lane][8]: tap=s>>1; ic=(s&1)*32+(l>>4)*8+j
        int u = bid - 537;
        int s = u >> 1, nh = u & 1;
        int n = nh * 4 + (tid >> 6), l = tid & 63;
        int oc = n * 16 + (l & 15);
        int tap = s >> 1;
        ushort8 hi, lo;
        #pragma unroll
        for (int j = 0; j < 8; ++j) {
            int ic = (s & 1) * 32 + (l >> 4) * 8 + j;
            float v = w2[oc * 576 + ic * 9 + tap];
            unsigned short h = f2bf(v);
            hi[j] = h; lo[j] = f2bf(v - bf2f(h));
        }
        int idx = ((s * 8 + n) * 64 + l) * 8;
        *(ushort8*)(wB2h + idx) = hi;  *(ushort8*)(wB2l + idx) = lo;
    }
}

struct Ops {
    bf16x8 Ah0, Ah1, Al0, Al1;
    bf16x8 Bh0, Bh1, Bh2, Bh3, Bl0, Bl1, Bl2, Bl3;
};

// -------------------------------------------------------------------------
// k1: conv1 7x7 (12->64) + bias + ReLU + maxpool via MFMA implicit GEMM.
// grid 1024 = b(8) x y0(64) x xh(2); wave: 16-col strip, 2 row-frags, 64 oc.
// Depth-1 register double-buffer: prefetch step s+1 while MFMAing step s.
// -------------------------------------------------------------------------
__global__ __launch_bounds__(256, 3) void k1_mfma(
    const unsigned short* __restrict__ imTh, const unsigned short* __restrict__ imTl,
    const unsigned short* __restrict__ wB1h, const unsigned short* __restrict__ wB1l,
    const float* __restrict__ b1,
    unsigned short* __restrict__ pTh, unsigned short* __restrict__ pTl)
{
    const int bid = blockIdx.x;
    const int b  = bid & 7;
    const int rest = bid >> 3;
    const int y0 = rest & 63;
    const int x0 = (rest >> 6) * 64;
    const int tid = threadIdx.x;
    const int w  = __builtin_amdgcn_readfirstlane(tid >> 6);
    const int l  = tid & 63;
    const int px = l & 15;
    const int g  = l >> 4;
    const int gq = g >> 1;                  // tap parity
    const int baseA = ((b * 136 + 2 * y0) * 136 + (x0 + w * 16 + px)) * 16 + (g & 1) * 8;

    f32x4 acc[2][4];
    #pragma unroll
    for (int m = 0; m < 2; ++m)
        #pragma unroll
        for (int n = 0; n < 4; ++n) acc[m][n] = (f32x4)(0.0f);

#define K1_LOAD(O, s) { \
    const int t0 = 2 * (s), t1 = 2 * (s) + 1; \
    const int o0 = ((t0 / 7) * 136 + (t0 % 7)) * 16; \
    const int o1 = ((t1 / 7) * 136 + (t1 % 7)) * 16; \
    int offA = gq ? o1 : o0; \
    O.Ah0 = *(const bf16x8*)(imTh + baseA + offA); \
    O.Ah1 = *(const bf16x8*)(imTh + baseA + 2176 + offA); \
    O.Al0 = *(const bf16x8*)(imTl + baseA + offA); \
    O.Al1 = *(const bf16x8*)(imTl + baseA + 2176 + offA); \
    const unsigned short* wb  = wB1h + (s) * 2048 + l * 8; \
    const unsigned short* wl2 = wB1l + (s) * 2048 + l * 8; \
    O.Bh0 = *(const bf16x8*)(wb);         O.Bh1 = *(const bf16x8*)(wb + 512); \
    O.Bh2 = *(const bf16x8*)(wb + 1024);  O.Bh3 = *(const bf16x8*)(wb + 1536); \
    O.Bl0 = *(const bf16x8*)(wl2);        O.Bl1 = *(const bf16x8*)(wl2 + 512); \
    O.Bl2 = *(const bf16x8*)(wl2 + 1024); O.Bl3 = *(const bf16x8*)(wl2 + 1536); }

#define K1_MFMA_N(O, n) \
    acc[0][n] = __builtin_amdgcn_mfma_f32_16x16x32_bf16(O.Ah0, O.Bh##n, acc[0][n], 0, 0, 0); \
    acc[0][n] = __builtin_amdgcn_mfma_f32_16x16x32_bf16(O.Ah0, O.Bl##n, acc[0][n], 0, 0, 0); \
    acc[0][n] = __builtin_amdgcn_mfma_f32_16x16x32_bf16(O.Al0, O.Bh##n, acc[0][n], 0, 0, 0); \
    acc[1][n] = __builtin_amdgcn_mfma_f32_16x16x32_bf16(O.Ah1, O.Bh##n, acc[1][n], 0, 0, 0); \
    acc[1][n] = __builtin_amdgcn_mfma_f32_16x16x32_bf16(O.Ah1, O.Bl##n, acc[1][n], 0, 0, 0); \
    acc[1][n] = __builtin_amdgcn_mfma_f32_16x16x32_bf16(O.Al1, O.Bh##n, acc[1][n], 0, 0, 0);

#define K1_MFMA_ALL(O) { K1_MFMA_N(O, 0) K1_MFMA_N(O, 1) K1_MFMA_N(O, 2) K1_MFMA_N(O, 3) }

    Ops oA, oB;
    K1_LOAD(oA, 0)
    #pragma unroll
    for (int s = 0; s < 25; ++s) {
        if ((s & 1) == 0) {
            if (s < 24) { K1_LOAD(oB, s + 1) }
            K1_MFMA_ALL(oA)
        } else {
            if (s < 24) { K1_LOAD(oA, s + 1) }
            K1_MFMA_ALL(oB)
        }
    }
#undef K1_LOAD
#undef K1_MFMA_N
#undef K1_MFMA_ALL

    // epilogue: bias + maxpool(2x2) + ReLU, write bf16 hi/lo into poolTp
    #pragma unroll
    for (int n = 0; n < 4; ++n) {
        int oc = n * 16 + px;
        float bias = b1[oc];
        #pragma unroll
        for (int pp = 0; pp < 2; ++pp) {
            int e = pp * 2;
            float m = fmaxf(fmaxf(acc[0][n][e], acc[0][n][e + 1]),
                            fmaxf(acc[1][n][e], acc[1][n][e + 1]));
            float v = fmaxf(m + bias, 0.0f);
            unsigned short h = f2bf(v);
            unsigned short lo = f2bf(v - bf2f(h));
            int pcol = (x0 >> 1) + w * 8 + g * 2 + pp;
            int pidx = ((b * 66 + y0 + 1) * 66 + pcol + 1) * 64 + oc;
            pTh[pidx] = h; pTl[pidx] = lo;
        }
    }
}

// -------------------------------------------------------------------------
// k2: conv2 3x3 (64->128) + bias + ReLU + pos-emb via MFMA implicit GEMM.
// grid 512 = b(8) x y2(32 row-pairs) x ocg(2: 64 oc). Wave: 32-col strip
// (2 M-frags) x 64 oc; w>>1 selects row, w&1 selects col-half.
// K = 18 steps x 32. Depth-1 register double-buffer.
// -------------------------------------------------------------------------
__global__ __launch_bounds__(256, 3) void k2_mfma(
    const unsigned short* __restrict__ pTh, const unsigned short* __restrict__ pTl,
    const unsigned short* __restrict__ wB2h, const unsigned short* __restrict__ wB2l,
    const float* __restrict__ b2, const float* __restrict__ pew,
    const float* __restrict__ peb, float* __restrict__ x2)
{
    const int bid = blockIdx.x;
    const int b   = bid & 7;
    const int rest = bid >> 3;
    const int y2  = rest & 31;
    const int ocg = rest >> 5;              // 0..1
    const int tid = threadIdx.x;
    const int w  = __builtin_amdgcn_readfirstlane(tid >> 6);
    const int l  = tid & 63;
    const int px = l & 15;
    const int g  = l >> 4;
    const int y     = y2 * 2 + (w >> 1);
    const int xbase = (w & 1) * 32;
    const int baseA = ((b * 66 + y) * 66 + (xbase + px)) * 64 + g * 8;

    f32x4 acc[2][4];
    #pragma unroll
    for (int m = 0; m < 2; ++m)
        #pragma unroll
        for (int n = 0; n < 4; ++n) acc[m][n] = (f32x4)(0.0f);

#define K2_LOAD(O, s) { \
    const int tap = (s) >> 1; \
    const int offA = ((tap / 3) * 66 + (tap % 3)) * 64 + ((s) & 1) * 32; \
    O.Ah0 = *(const bf16x8*)(pTh + baseA + offA); \
    O.Ah1 = *(const bf16x8*)(pTh + baseA + 1024 + offA); \
    O.Al0 = *(const bf16x8*)(pTl + baseA + offA); \
    O.Al1 = *(const bf16x8*)(pTl + baseA + 1024 + offA); \
    const unsigned short* wb  = wB2h + (s) * 4096 + ocg * 2048 + l * 8; \
    const unsigned short* wl2 = wB2l + (s) * 4096 + ocg * 2048 + l * 8; \
    O.Bh0 = *(const bf16x8*)(wb);         O.Bh1 = *(const bf16x8*)(wb + 512); \
    O.Bh2 = *(const bf16x8*)(wb + 1024);  O.Bh3 = *(const bf16x8*)(wb + 1536); \
    O.Bl0 = *(const bf16x8*)(wl2);        O.Bl1 = *(const bf16x8*)(wl2 + 512); \
    O.Bl2 = *(const bf16x8*)(wl2 + 1024); O.Bl3 = *(const bf16x8*)(wl2 + 1536); }

#define K2_MFMA_N(O, n) \
    acc[0][n] = __builtin_amdgcn_mfma_f32_16x16x32_bf16(O.Ah0, O.Bh##n, acc[0][n], 0, 0, 0); \
    acc[0][n] = __builtin_amdgcn_mfma_f32_16x16x32_bf16(O.Ah0, O.Bl##n, acc[0][n], 0, 0, 0); \
    acc[0][n] = __builtin_amdgcn_mfma_f32_16x16x32_bf16(O.Al0, O.Bh##n, acc[0][n], 0, 0, 0); \
    acc[1][n] = __builtin_amdgcn_mfma_f32_16x16x32_bf16(O.Ah1, O.Bh##n, acc[1][n], 0, 0, 0); \
    acc[1][n] = __builtin_amdgcn_mfma_f32_16x16x32_bf16(O.Ah1, O.Bl##n, acc[1][n], 0, 0, 0); \
    acc[1][n] = __builtin_amdgcn_mfma_f32_16x16x32_bf16(O.Al1, O.Bh##n, acc[1][n], 0, 0, 0);

#define K2_MFMA_ALL(O) { K2_MFMA_N(O, 0) K2_MFMA_N(O, 1) K2_MFMA_N(O, 2) K2_MFMA_N(O, 3) }

    Ops oA, oB;
    K2_LOAD(oA, 0)
    #pragma unroll
    for (int s = 0; s < 18; ++s) {
        if ((s & 1) == 0) {
            if (s < 17) { K2_LOAD(oB, s + 1) }
            K2_MFMA_ALL(oA)
        } else {
            if (s < 17) { K2_LOAD(oA, s + 1) }
            K2_MFMA_ALL(oB)
        }
    }
#undef K2_LOAD
#undef K2_MFMA_N
#undef K2_MFMA_ALL

    // epilogue: bias + ReLU + position embedding (grid value = i/63), f32 store
    const float inv63 = 1.0f / 63.0f;
    float yn = (float)y * inv63;
    #pragma unroll
    for (int n = 0; n < 4; ++n) {
        int oc = ocg * 64 + n * 16 + px;
        float bias = b2[oc];
        float e0 = pew[oc * 4 + 0], e1 = pew[oc * 4 + 1];
        float e2 = pew[oc * 4 + 2], e3 = pew[oc * 4 + 3];
        float rowc = peb[oc] + yn * e0 + (1.0f - yn) * e2;
        #pragma unroll
        for (int mm = 0; mm < 2; ++mm) {
            f32x4 st;
            #pragma unroll
            for (int e = 0; e < 4; ++e) {
                int x = xbase + mm * 16 + g * 4 + e;
                float xn = (float)x * inv63;
                st[e] = fmaxf(acc[mm][n][e] + bias, 0.0f) + rowc + xn * e1 + (1.0f - xn) * e3;
            }
            *(f32x4*)&x2[((b * 128 + oc) * 64 + y) * 64 + xbase + mm * 16 + g * 4] = st;
        }
    }
}

// -------------------------------------------------------------------------
// k3: masked spatial max partials. (unchanged)
// -------------------------------------------------------------------------
__global__ __launch_bounds__(256, 4) void k_roi(
    const float* __restrict__ x2, const int* __restrict__ rois,
    float* __restrict__ partial)
{
    __shared__ float mlds[16 * 512];
    const int tid = threadIdx.x;
    const int bid = blockIdx.x;
    const int b    = bid & 7;
    const int rest = bid >> 3;
    const int og   = rest & 1;
    const int pe   = (rest >> 1) & 7;
    const int cg   = rest >> 4;

    for (int idx = tid; idx < 16 * 512; idx += 256) {
        int ol = idx >> 9;
        int pp = idx & 511;
        int pxx = pe * 512 + pp;
        int h = pxx >> 6, ww = pxx & 63;
        mlds[idx] = rois[((b * 32 + og * 16 + ol) << 14) + (h << 8) + (ww << 1)] ? 1.0f : 0.0f;
    }
    __syncthreads();

    const int waveU = __builtin_amdgcn_readfirstlane(tid >> 6);
    const int lane  = tid & 63;
    const int c0    = cg * 16 + waveU * 4;

    float acc[4][16];
    #pragma unroll
    for (int c = 0; c < 4; ++c)
        #pragma unroll
        for (int o = 0; o < 16; ++o) acc[c][o] = -INFINITY;

    #pragma unroll 1
    for (int step = 0; step < 8; ++step) {
        int pp = step * 64 + lane;
        float m[16];
        #pragma unroll
        for (int o = 0; o < 16; ++o) m[o] = mlds[o * 512 + pp];
        const float* xb = &x2[(b * 128 + c0) * 4096 + pe * 512 + pp];
        #pragma unroll
        for (int c = 0; c < 4; ++c) {
            float x = xb[c * 4096];
            #pragma unroll
            for (int o = 0; o < 16; ++o)
                acc[c][o] = fmaxf(acc[c][o], x * m[o]);
        }
    }

    #pragma unroll
    for (int c = 0; c < 4; ++c)
        #pragma unroll
        for (int o = 0; o < 16; ++o) {
            float v = acc[c][o];
            #pragma unroll
            for (int mm = 1; mm < 64; mm <<= 1)
                v = fmaxf(v, __shfl_xor(v, mm, 64));
            if (lane == o * 4 + c)
                partial[((b * 32 + og * 16 + o) * 8 + pe) * 128 + c0 + c] = v;
        }
}

// k4: reduce the 8 pixel-chunk partials -> out[8][32][128]
__global__ void k_reduce(const float* __restrict__ partial, float* __restrict__ out) {
    int idx = blockIdx.x * 256 + threadIdx.x;   // 32768
    int c  = idx & 127;
    int bo = idx >> 7;
    float v = partial[bo * 8 * 128 + c];
    #pragma unroll
    for (int pe = 1; pe < 8; ++pe)
        v = fmaxf(v, partial[(bo * 8 + pe) * 128 + c]);
    out[idx] = v;
}

extern "C" void kernel_launch(void* const* d_in, const int* in_sizes, int n_in,
                              void* d_out, int out_size, void* d_ws, size_t ws_size,
                              hipStream_t stream) {
    const float* images = (const float*)d_in[0];
    const int*   rois   = (const int*)d_in[1];
    // d_in[2] = gt_pos (unused)
    const float* w1  = (const float*)d_in[3];
    const float* b1  = (const float*)d_in[4];
    const float* w2  = (const float*)d_in[5];
    const float* b2  = (const float*)d_in[6];
    const float* pew = (const float*)d_in[7];
    const float* peb = (const float*)d_in[8];
    float* out = (float*)d_out;

    unsigned short* imTh = (unsigned short*)d_ws;
    unsigned short* imTl = imTh + N_IMT;
    unsigned short* pTh  = imTl + N_IMT;
    unsigned short* pTl  = pTh  + N_PT;
    float* x2      = (float*)(pTl + N_PT);
    float* partial = x2 + N_X2;
    unsigned short* wB1h = (unsigned short*)(partial + N_PARTIAL);
    unsigned short* wB1l = wB1h + N_WB1;
    unsigned short* wB2h = wB1l + N_WB1;
    unsigned short* wB2l = wB2h + N_WB2;

    const int nzero = (2 * N_IMT + 2 * N_PT) / 2;   // u32 count
    k_zero<<<2048, 256, 0, stream>>>((unsigned*)d_ws, nzero);
    k_prep<<<573, 256, 0, stream>>>(images, w1, w2, imTh, imTl, wB1h, wB1l, wB2h, wB2l);
    k1_mfma<<<1024, 256, 0, stream>>>(imTh, imTl, wB1h, wB1l, b1, pTh, pTl);
    k2_mfma<<<512, 256, 0, stream>>>(pTh, pTl, wB2h, wB2l, b2, pew, peb, x2);
    k_roi<<<1024, 256, 0, stream>>>(x2, rois, partial);
    k_reduce<<<128, 256, 0, stream>>>(partial, out);
}